// Round 1
// baseline (258.454 us; speedup 1.0000x reference)
//
#include <hip/hip_runtime.h>

// DilatedReparamBlock folded into one 13x13 depthwise conv + bias.
//
// R4 change: occupancy + register-pressure fix.
//  - 128-thread blocks (2 waves) share one plane's LDS tile: same 19456 B
//    per block -> 8 blocks/CU -> 16 waves/CU = 4/SIMD (was 2/SIMD).
//  - Per-thread tile 7 rows x 4 cols (xg = tid&15, 14 active; yg = tid>>4,
//    8 row-strips of 7). Same 12.5% idle-lane ratio as the 7x8 layout.
//  - Merged weights are wave-uniform -> hoisted to SGPRs via readfirstlane,
//    freeing ~50 VGPRs so the compiler can pipeline window loads under FMAs.
//  - ky processed in groups of 4 (+ tail ky=12): each staged input row read
//    once per group serves 4 weight rows -> 148 ds_read_b128/thread (was 275
//    equivalent), keeping the per-CU LDS pipe under the VALU floor.
//  - Bank-quad check: word addr = 68*(7yg+ri) + 4xg + 4q -> class
//    (28yg + 4xg) mod 32; per wave each quad carries 8 distinct addresses
//    = the b128 minimum. Idle lanes clamp xg-8 -> broadcast (free).

#define CCH 384
#define SP 56
#define PW 68              // 56 + 2*6 padding
#define NPLANES (16*384)

__device__ __forceinline__ float rfl(float v) {
    return __int_as_float(__builtin_amdgcn_readfirstlane(__float_as_int(v)));
}

__global__ __launch_bounds__(128, 4) void drb_conv13_w128(
    const float* __restrict__ x,
    const float* __restrict__ w_lk, const float* __restrict__ w_b0,
    const float* __restrict__ w_b1, const float* __restrict__ w_b2,
    const float* __restrict__ w_b3, const float* __restrict__ w_b4,
    const float* __restrict__ w_b5,
    const float* __restrict__ gamma, const float* __restrict__ beta,
    const float* __restrict__ mean, const float* __restrict__ var,
    float* __restrict__ out)
{
    __shared__ __align__(16) float sx[PW * PW];   // 18496 B padded plane
    __shared__ __align__(16) float sw[13 * 16];   // merged weights, rows padded to 16

    const int plane = blockIdx.x;                 // n*384 + c
    const int c = plane % CCH;
    const int tid = threadIdx.x;
    const float* __restrict__ xp = x + (size_t)plane * (SP * SP);

    // --- BN fold constants (wave-uniform -> scalar loads) ---
    float S[7];
    float bias = 0.f;
    #pragma unroll
    for (int j = 0; j < 7; j++) {
        float inv = gamma[j * CCH + c] * rsqrtf(var[j * CCH + c] + 1e-5f);
        S[j] = inv;
        bias += beta[j * CCH + c] - mean[j * CCH + c] * inv;
    }

    // --- zero padded tile (b128 stores) ---
    {
        float4 z = make_float4(0.f, 0.f, 0.f, 0.f);
        #pragma unroll
        for (int k = 0; k < 10; k++) {
            int i = tid + 128 * k;
            if (i < PW * PW / 4) ((float4*)sx)[i] = z;
        }
    }
    __syncthreads();   // 2 waves: zero must complete before interior staging

    // --- build merged 13x13 weights (208 slots incl. row pad) ---
    #pragma unroll
    for (int k = 0; k < 2; k++) {
        int t = tid + 128 * k;
        if (t < 13 * 16) {
            int ky = t >> 4, kx = t & 15;
            float w = 0.f;
            if (kx < 13) {
                w = S[0] * w_lk[c * 169 + ky * 13 + kx];                   // 13x13 d1
                if (ky >= 4 && ky <= 8 && kx >= 4 && kx <= 8)              // 5x5 d1 @4
                    w += S[1] * w_b0[c * 25 + (ky - 4) * 5 + (kx - 4)];
                if (ky >= 3 && ky <= 9 && kx >= 3 && kx <= 9)              // 7x7 d1 @3
                    w += S[2] * w_b1[c * 49 + (ky - 3) * 7 + (kx - 3)];
                if (!(ky & 1) && !(kx & 1))                                // 7x7 d2
                    w += S[3] * w_b2[c * 49 + (ky >> 1) * 7 + (kx >> 1)];
                if (ky >= 3 && ky <= 9 && (ky - 3) % 3 == 0 &&
                    kx >= 3 && kx <= 9 && (kx - 3) % 3 == 0)               // 3x3 d3
                    w += S[4] * w_b3[c * 9 + ((ky - 3) / 3) * 3 + (kx - 3) / 3];
                if (ky >= 2 && ky <= 10 && (ky - 2) % 4 == 0 &&
                    kx >= 2 && kx <= 10 && (kx - 2) % 4 == 0)              // 3x3 d4
                    w += S[5] * w_b4[c * 9 + ((ky - 2) / 4) * 3 + (kx - 2) / 4];
                if (ky >= 1 && ky <= 11 && (ky - 1) % 5 == 0 &&
                    kx >= 1 && kx <= 11 && (kx - 1) % 5 == 0)              // 3x3 d5
                    w += S[6] * w_b5[c * 9 + ((ky - 1) / 5) * 3 + (kx - 1) / 5];
            }
            sw[t] = w;
        }
    }

    // --- stage plane: 784 float4 global loads -> 2x b64 LDS writes each ---
    #pragma unroll
    for (int k = 0; k < 7; k++) {
        int i4 = tid + 128 * k;
        if (i4 < SP * SP / 4) {
            float4 v = ((const float4*)xp)[i4];
            int r = i4 / 14;                 // 14 float4 per 56-wide row
            int col = (i4 - r * 14) * 4;
            float* d = &sx[(r + 6) * PW + col + 6];   // word-even -> 8B aligned
            ((float2*)d)[0] = make_float2(v.x, v.y);
            ((float2*)d)[1] = make_float2(v.z, v.w);
        }
    }
    __syncthreads();

    // --- compute: lane (xg,yg) -> out rows [7yg..7yg+6], cols [4xg..4xg+3] ---
    const int xg = tid & 15;
    const int yg = tid >> 4;
    const int xgc = (xg < 14) ? xg : (xg - 8);   // idle lanes broadcast with xg-8
    const int Yb = yg * 7;
    const float* __restrict__ sbase = &sx[Yb * PW + 4 * xgc];

    float acc[7][4];
    #pragma unroll
    for (int r = 0; r < 7; r++)
        #pragma unroll
        for (int j = 0; j < 4; j++) acc[r][j] = 0.f;

    // ky groups of 4: rows k0..k0+9 each read once, serve 4 weight rows.
    #pragma unroll 1
    for (int k0 = 0; k0 < 12; k0 += 4) {
        float w[4][13];   // wave-uniform -> SGPRs via readfirstlane
        #pragma unroll
        for (int dy = 0; dy < 4; dy++) {
            const float* wr = &sw[(k0 + dy) * 16];
            float4 a = ((const float4*)wr)[0];
            float4 b = ((const float4*)wr)[1];
            float4 cq = ((const float4*)wr)[2];
            float dl = wr[12];
            w[dy][0] = rfl(a.x);  w[dy][1] = rfl(a.y);
            w[dy][2] = rfl(a.z);  w[dy][3] = rfl(a.w);
            w[dy][4] = rfl(b.x);  w[dy][5] = rfl(b.y);
            w[dy][6] = rfl(b.z);  w[dy][7] = rfl(b.w);
            w[dy][8] = rfl(cq.x); w[dy][9] = rfl(cq.y);
            w[dy][10] = rfl(cq.z); w[dy][11] = rfl(cq.w);
            w[dy][12] = rfl(dl);
        }
        const float* sr = sbase + k0 * PW;
        #pragma unroll
        for (int i = 0; i < 10; i++) {
            float4 win4[4];
            #pragma unroll
            for (int q = 0; q < 4; q++)
                win4[q] = *(const float4*)(sr + i * PW + 4 * q);
            const float* win = (const float*)win4;
            #pragma unroll
            for (int dy = 0; dy < 4; dy++) {
                const int r = i - dy;
                if (r >= 0 && r < 7) {
                    #pragma unroll
                    for (int kx = 0; kx < 13; kx++) {
                        const float wv = w[dy][kx];
                        #pragma unroll
                        for (int j = 0; j < 4; j++)
                            acc[r][j] = fmaf(wv, win[kx + j], acc[r][j]);
                    }
                }
            }
        }
    }
    // tail ky = 12
    {
        float w12[13];
        const float* wr = &sw[12 * 16];
        float4 a = ((const float4*)wr)[0];
        float4 b = ((const float4*)wr)[1];
        float4 cq = ((const float4*)wr)[2];
        float dl = wr[12];
        w12[0] = rfl(a.x);  w12[1] = rfl(a.y);  w12[2] = rfl(a.z);  w12[3] = rfl(a.w);
        w12[4] = rfl(b.x);  w12[5] = rfl(b.y);  w12[6] = rfl(b.z);  w12[7] = rfl(b.w);
        w12[8] = rfl(cq.x); w12[9] = rfl(cq.y); w12[10] = rfl(cq.z); w12[11] = rfl(cq.w);
        w12[12] = rfl(dl);
        const float* sr = sbase + 12 * PW;
        #pragma unroll
        for (int i = 0; i < 7; i++) {
            float4 win4[4];
            #pragma unroll
            for (int q = 0; q < 4; q++)
                win4[q] = *(const float4*)(sr + i * PW + 4 * q);
            const float* win = (const float*)win4;
            #pragma unroll
            for (int kx = 0; kx < 13; kx++) {
                const float wv = w12[kx];
                #pragma unroll
                for (int j = 0; j < 4; j++)
                    acc[i][j] = fmaf(wv, win[kx + j], acc[i][j]);
            }
        }
    }

    // --- epilogue: +bias, one float4 store per row, idle col groups masked ---
    if (xg < 14) {
        float* op = out + (size_t)plane * (SP * SP) + Yb * SP + 4 * xg;
        #pragma unroll
        for (int r = 0; r < 7; r++) {
            *(float4*)(op + r * SP) = make_float4(acc[r][0] + bias, acc[r][1] + bias,
                                                  acc[r][2] + bias, acc[r][3] + bias);
        }
    }
}

extern "C" void kernel_launch(void* const* d_in, const int* in_sizes, int n_in,
                              void* d_out, int out_size, void* d_ws, size_t ws_size,
                              hipStream_t stream) {
    const float* x    = (const float*)d_in[0];
    const float* w_lk = (const float*)d_in[1];
    const float* w_b0 = (const float*)d_in[2];
    const float* w_b1 = (const float*)d_in[3];
    const float* w_b2 = (const float*)d_in[4];
    const float* w_b3 = (const float*)d_in[5];
    const float* w_b4 = (const float*)d_in[6];
    const float* w_b5 = (const float*)d_in[7];
    const float* bn_g = (const float*)d_in[8];
    const float* bn_b = (const float*)d_in[9];
    const float* bn_m = (const float*)d_in[10];
    const float* bn_v = (const float*)d_in[11];
    float* out = (float*)d_out;

    drb_conv13_w128<<<dim3(NPLANES), dim3(128), 0, stream>>>(
        x, w_lk, w_b0, w_b1, w_b2, w_b3, w_b4, w_b5,
        bn_g, bn_b, bn_m, bn_v, out);
}

// Round 4
// 227.125 us; speedup vs baseline: 1.1379x; 1.1379x over previous
//
#include <hip/hip_runtime.h>

// DilatedReparamBlock folded into one 13x13 depthwise conv + bias.
//
// R7 = R5 resubmitted again (R5: container failed; R6: broker at capacity —
// no kernel data either round). Static audit clean; keeping the A/B against
// R3 (144 us) intact by not editing blind.
//
// R5 theory: R4 showed occupancy 2x -> VALUBusy unchanged at 47%, so the
// limiter is per-CU LDS read throughput. This version cuts LDS window reads
// per FMA:
//  - R3's 64-thread / 7x8-tile layout (cheapest measured conflict rate:
//    13 cyc extra per b128 vs 19 for the 4-col layout);
//  - ky in groups of 4 (+ ky=12 tail) with row reuse: 37 row-reads x 5 b128
//    = 185 reads per lane (was 275, -33%);
//  - group weights (4x13) hoisted to SGPRs via readfirstlane;
//  - x prefetched to registers before the zero/weight phases.

#define CCH 384
#define SP 56
#define PW 68              // 56 + 2*6 padding
#define NPLANES (16*384)

__device__ __forceinline__ float rfl(float v) {
    return __int_as_float(__builtin_amdgcn_readfirstlane(__float_as_int(v)));
}

__global__ __launch_bounds__(64, 2) void drb_conv13_r7(
    const float* __restrict__ x,
    const float* __restrict__ w_lk, const float* __restrict__ w_b0,
    const float* __restrict__ w_b1, const float* __restrict__ w_b2,
    const float* __restrict__ w_b3, const float* __restrict__ w_b4,
    const float* __restrict__ w_b5,
    const float* __restrict__ gamma, const float* __restrict__ beta,
    const float* __restrict__ mean, const float* __restrict__ var,
    float* __restrict__ out)
{
    __shared__ __align__(16) float sx[PW * PW];   // 18496 B padded plane
    __shared__ __align__(16) float sw[13 * 16];   // merged weights, rows padded to 16

    const int plane = blockIdx.x;                 // n*384 + c
    const int c = plane % CCH;
    const int tid = threadIdx.x;
    const float* __restrict__ xp = x + (size_t)plane * (SP * SP);

    // --- prefetch plane into registers (HBM latency hides under LDS init) ---
    float4 stage[13];
    #pragma unroll
    for (int k = 0; k < 13; k++) {
        int i4 = tid + 64 * k;
        if (i4 < SP * SP / 4) stage[k] = ((const float4*)xp)[i4];
    }

    // --- BN fold constants (wave-uniform -> scalar loads) ---
    float S[7];
    float bias = 0.f;
    #pragma unroll
    for (int j = 0; j < 7; j++) {
        float inv = gamma[j * CCH + c] * rsqrtf(var[j * CCH + c] + 1e-5f);
        S[j] = inv;
        bias += beta[j * CCH + c] - mean[j * CCH + c] * inv;
    }

    // --- zero padded tile (b128 stores); single wave -> ops stay ordered ---
    {
        float4 z = make_float4(0.f, 0.f, 0.f, 0.f);
        #pragma unroll
        for (int k = 0; k < 19; k++) {
            int i = tid + 64 * k;
            if (i < PW * PW / 4) ((float4*)sx)[i] = z;
        }
    }

    // --- build merged 13x13 weights (208 slots incl. row pad) ---
    #pragma unroll
    for (int k = 0; k < 4; k++) {
        int t = tid + 64 * k;
        if (t < 13 * 16) {
            int ky = t >> 4, kx = t & 15;
            float w = 0.f;
            if (kx < 13) {
                w = S[0] * w_lk[c * 169 + ky * 13 + kx];                   // 13x13 d1
                if (ky >= 4 && ky <= 8 && kx >= 4 && kx <= 8)              // 5x5 d1 @4
                    w += S[1] * w_b0[c * 25 + (ky - 4) * 5 + (kx - 4)];
                if (ky >= 3 && ky <= 9 && kx >= 3 && kx <= 9)              // 7x7 d1 @3
                    w += S[2] * w_b1[c * 49 + (ky - 3) * 7 + (kx - 3)];
                if (!(ky & 1) && !(kx & 1))                                // 7x7 d2
                    w += S[3] * w_b2[c * 49 + (ky >> 1) * 7 + (kx >> 1)];
                if (ky >= 3 && ky <= 9 && (ky - 3) % 3 == 0 &&
                    kx >= 3 && kx <= 9 && (kx - 3) % 3 == 0)               // 3x3 d3
                    w += S[4] * w_b3[c * 9 + ((ky - 3) / 3) * 3 + (kx - 3) / 3];
                if (ky >= 2 && ky <= 10 && (ky - 2) % 4 == 0 &&
                    kx >= 2 && kx <= 10 && (kx - 2) % 4 == 0)              // 3x3 d4
                    w += S[5] * w_b4[c * 9 + ((ky - 2) / 4) * 3 + (kx - 2) / 4];
                if (ky >= 1 && ky <= 11 && (ky - 1) % 5 == 0 &&
                    kx >= 1 && kx <= 11 && (kx - 1) % 5 == 0)              // 3x3 d5
                    w += S[6] * w_b5[c * 9 + ((ky - 1) / 5) * 3 + (kx - 1) / 5];
            }
            sw[t] = w;
        }
    }

    // --- write staged plane into LDS (after zero; same-wave LDS ops ordered) ---
    #pragma unroll
    for (int k = 0; k < 13; k++) {
        int i4 = tid + 64 * k;
        if (i4 < SP * SP / 4) {
            int r = i4 / 14;                 // 14 float4 per 56-wide row
            int col = (i4 - r * 14) * 4;
            float* d = &sx[(r + 6) * PW + col + 6];   // word-even -> 8B aligned
            ((float2*)d)[0] = make_float2(stage[k].x, stage[k].y);
            ((float2*)d)[1] = make_float2(stage[k].z, stage[k].w);
        }
    }
    __syncthreads();

    // --- compute: lane (xg,yg) -> out rows [7yg..7yg+6], cols [8xg..8xg+7] ---
    const int xg = tid & 7;
    const int yg = tid >> 3;
    const int xgc = (xg < 7) ? xg : 3;       // idle lane: same-address broadcast with xg=3
    const int Yb = yg * 7;
    const float* __restrict__ sbase = &sx[Yb * PW + 8 * xgc];

    float acc[7][8];
    #pragma unroll
    for (int r = 0; r < 7; r++)
        #pragma unroll
        for (int j = 0; j < 8; j++) acc[r][j] = 0.f;

    // ky groups of 4: input rows k0..k0+9 each read ONCE, serve 4 weight rows.
    #pragma unroll 1
    for (int k0 = 0; k0 < 12; k0 += 4) {
        float w[4][13];   // wave-uniform -> SGPRs via readfirstlane
        #pragma unroll
        for (int dy = 0; dy < 4; dy++) {
            const float* wr = &sw[(k0 + dy) * 16];
            #pragma unroll
            for (int q = 0; q < 3; q++) {
                float4 t = ((const float4*)wr)[q];
                w[dy][4*q+0] = rfl(t.x); w[dy][4*q+1] = rfl(t.y);
                w[dy][4*q+2] = rfl(t.z); w[dy][4*q+3] = rfl(t.w);
            }
            w[dy][12] = rfl(wr[12]);
        }
        const float* sr = sbase + k0 * PW;
        #pragma unroll
        for (int i = 0; i < 10; i++) {
            float4 win4[5];
            #pragma unroll
            for (int q = 0; q < 5; q++)
                win4[q] = *(const float4*)(sr + i * PW + 4 * q);
            const float* win = (const float*)win4;
            #pragma unroll
            for (int dy = 0; dy < 4; dy++) {
                const int r = i - dy;
                if (r >= 0 && r < 7) {
                    #pragma unroll
                    for (int kx = 0; kx < 13; kx++) {
                        const float wv = w[dy][kx];
                        #pragma unroll
                        for (int j = 0; j < 8; j++)
                            acc[r][j] = fmaf(wv, win[kx + j], acc[r][j]);
                    }
                }
            }
        }
    }
    // tail ky = 12 (rows Yb+12..Yb+18)
    {
        float w12[13];
        const float* wr = &sw[12 * 16];
        #pragma unroll
        for (int q = 0; q < 3; q++) {
            float4 t = ((const float4*)wr)[q];
            w12[4*q+0] = rfl(t.x); w12[4*q+1] = rfl(t.y);
            w12[4*q+2] = rfl(t.z); w12[4*q+3] = rfl(t.w);
        }
        w12[12] = rfl(wr[12]);
        const float* sr = sbase + 12 * PW;
        #pragma unroll
        for (int i = 0; i < 7; i++) {
            float4 win4[5];
            #pragma unroll
            for (int q = 0; q < 5; q++)
                win4[q] = *(const float4*)(sr + i * PW + 4 * q);
            const float* win = (const float*)win4;
            #pragma unroll
            for (int kx = 0; kx < 13; kx++) {
                const float wv = w12[kx];
                #pragma unroll
                for (int j = 0; j < 8; j++)
                    acc[i][j] = fmaf(wv, win[kx + j], acc[i][j]);
            }
        }
    }

    // --- epilogue: +bias, 2x float4 stores per row, idle col group masked ---
    if (xg < 7) {
        float* op = out + (size_t)plane * (SP * SP) + Yb * SP + 8 * xg;
        #pragma unroll
        for (int r = 0; r < 7; r++) {
            float4 v0 = make_float4(acc[r][0] + bias, acc[r][1] + bias,
                                    acc[r][2] + bias, acc[r][3] + bias);
            float4 v1 = make_float4(acc[r][4] + bias, acc[r][5] + bias,
                                    acc[r][6] + bias, acc[r][7] + bias);
            *(float4*)(op + r * SP) = v0;
            *(float4*)(op + r * SP + 4) = v1;
        }
    }
}

extern "C" void kernel_launch(void* const* d_in, const int* in_sizes, int n_in,
                              void* d_out, int out_size, void* d_ws, size_t ws_size,
                              hipStream_t stream) {
    const float* x    = (const float*)d_in[0];
    const float* w_lk = (const float*)d_in[1];
    const float* w_b0 = (const float*)d_in[2];
    const float* w_b1 = (const float*)d_in[3];
    const float* w_b2 = (const float*)d_in[4];
    const float* w_b3 = (const float*)d_in[5];
    const float* w_b4 = (const float*)d_in[6];
    const float* w_b5 = (const float*)d_in[7];
    const float* bn_g = (const float*)d_in[8];
    const float* bn_b = (const float*)d_in[9];
    const float* bn_m = (const float*)d_in[10];
    const float* bn_v = (const float*)d_in[11];
    float* out = (float*)d_out;

    drb_conv13_r7<<<dim3(NPLANES), dim3(64), 0, stream>>>(
        x, w_lk, w_b0, w_b1, w_b2, w_b3, w_b4, w_b5,
        bn_g, bn_b, bn_m, bn_v, out);
}